// Round 9
// baseline (308.811 us; speedup 1.0000x reference)
//
#include <hip/hip_runtime.h>
#include <math.h>

#define HH 512
#define FF 2048
#define BB 16
#define SS 2048
#define MM 32768  // BB*SS

using f32x4 = __attribute__((ext_vector_type(4))) float;
using s16x8 = __attribute__((ext_vector_type(8))) short;

struct __align__(8)  US4 { unsigned short x, y, z, w; };
struct __align__(16) US8 { unsigned short s[8]; };

__device__ __forceinline__ unsigned short f2bf(float f) {
  unsigned int u = __builtin_bit_cast(unsigned int, f);
  u += 0x7fffu + ((u >> 16) & 1u);
  return (unsigned short)(u >> 16);
}
__device__ __forceinline__ float bf2f(unsigned short u) {
  unsigned int x = ((unsigned int)u) << 16;
  return __builtin_bit_cast(float, x);
}
__device__ __forceinline__ void gload_lds16(const void* g, void* l) {
  __builtin_amdgcn_global_load_lds(
      (const __attribute__((address_space(1))) unsigned int*)g,
      (__attribute__((address_space(3))) unsigned int*)l, 16, 0, 0);
}

// ---- weight conversions (merged) ----
__global__ void k_conv(const float* __restrict__ We, const float* __restrict__ Wa,
                       unsigned short* __restrict__ OWe, unsigned short* __restrict__ OWa) {
  int bid = blockIdx.x, t = threadIdx.x;
  if (bid < 1024) {
    int idx = bid * 256 + t;  // < 262144
    f32x4 x = *(const f32x4*)(We + (size_t)idx * 4);
    US4 p{f2bf(x.x), f2bf(x.y), f2bf(x.z), f2bf(x.w)};
    *(US4*)(OWe + (size_t)idx * 4) = p;
  } else {
    int idx = (bid - 1024) * 256 + t;  // < 65536
    int k = idx >> 7, h4 = idx & 127;
    f32x4 x = *(const f32x4*)(Wa + (size_t)k * 1024 + 512 + h4 * 4);
    US4 p{f2bf(x.x), f2bf(x.y), f2bf(x.z), f2bf(x.w)};
    *(US4*)(OWa + (size_t)idx * 4) = p;
  }
}

// ---- h = hidden[-1] @ Wh.T + bh ----
__global__ void k_h(const float* __restrict__ hidden, const float* __restrict__ Wh,
                    const float* __restrict__ bh, float* __restrict__ h_ws) {
  int t = threadIdx.x, lane = t & 63, wid = t >> 6;
  int out = blockIdx.x * 4 + wid;  // < 8192
  int b = out >> 9, j = out & 511;
  const float* hr = hidden + (1) * BB * FF + b * FF;
  const float* wr = Wh + (size_t)j * FF;
  float a = 0.f;
#pragma unroll
  for (int i = 0; i < 8; ++i) {
    int o = i * 256 + lane * 4;
    f32x4 x = *(const f32x4*)(hr + o);
    f32x4 y = *(const f32x4*)(wr + o);
    a += x.x * y.x + x.y * y.y + x.z * y.z + x.w * y.w;
  }
#pragma unroll
  for (int m = 32; m; m >>= 1) a += __shfl_xor(a, m);
  if (lane == 0) h_ws[out] = a + bh[j];
}

// ---- bb[b][k] = ba[k] + h[b] . Wa[k, 0:512] ----
__global__ void k_bb(const float* __restrict__ h_ws, const float* __restrict__ Wa,
                     const float* __restrict__ ba, float* __restrict__ bb_ws) {
  int t = threadIdx.x, lane = t & 63, wid = t >> 6;
  int out = blockIdx.x * 4 + wid;  // < 8192
  int b = out >> 9, k = out & 511;
  const float* hr = h_ws + b * HH;
  const float* wa = Wa + (size_t)k * 1024;
  float a = 0.f;
#pragma unroll
  for (int i = 0; i < 2; ++i) {
    int o = i * 256 + lane * 4;
    f32x4 x = *(const f32x4*)(hr + o);
    f32x4 y = *(const f32x4*)(wa + o);
    a += x.x * y.x + x.y * y.y + x.z * y.z + x.w * y.w;
  }
#pragma unroll
  for (int m = 32; m; m >>= 1) a += __shfl_xor(a, m);
  if (lane == 0) bb_ws[out] = a + ba[k];
}

// ====== fused GEMM1 + GEMM2 + scores: counted-vmcnt half-K phase pipeline ======
// M=64 x N=512 per block (enc read once), 512 thr / 8 waves. 64 phases of 32 k.
// LDS 80KB => 2 blocks/CU: As0@0 | As1@8K | Bb0@16K(32K) | Bb1@48K(32K).
// Phase p (s=p>>1, H=p&1): issue B(p+1)->Bb[H^1] (+2 A-glb loads at H=0) ->
//   vmcnt(6) [counted: this phase's issues fly, B(p) landed] -> s_barrier ->
//   ds_read frags (+ds_write A(s+1)->As at H=1) -> lgkmcnt(0) -> s_barrier ->
//   16 MFMA. No vmcnt(0) drain in the loop (T3+T4). A-loads 2 steps deep.
// Subtiled conflict-free LDS (linear stage dest, 16-lane-linear frag reads):
//   B: byte=(kb*32+rowgrp)*256+rowlo*16 (kb 0..3); A: (kb*4+rowgrp)*256+rowlo*16.
template<int SPAR, int H, bool STB, bool LDA, bool WRA, int VM>
__device__ __forceinline__ void phase(
    const float* enc_m0, const unsigned short* Web, char* smem,
    int kt, int t, int lane, int wid, int sRow, int sKb, int sDst,
    const int* bRow, const int* bKb,
    f32x4& aL0, f32x4& aL1, const f32x4& aW0, const f32x4& aW1,
    f32x4 (&acc)[4][4]) {
  char* AsR = smem + SPAR * 8192;
  char* AsW = smem + (SPAR ^ 1) * 8192;
  char* BbR = smem + 16384 + H * 32768;
  char* BbW = smem + 16384 + (H ^ 1) * 32768;
  if (STB) {
    int kB = kt + (H + 1) * 32;
#pragma unroll
    for (int i = 0; i < 4; ++i) {
      int idx = i * 512 + t;
      gload_lds16(Web + (size_t)bRow[i] * FF + kB + bKb[i] * 8, BbW + idx * 16);
    }
  }
  if (LDA) {
    const float* p = enc_m0 + (size_t)sRow * FF + (kt + 128) + sKb * 8;
    aL0 = *(const f32x4*)p;
    aL1 = *(const f32x4*)(p + 4);
  }
  asm volatile("s_waitcnt vmcnt(%0)" :: "i"(VM) : "memory");
  __builtin_amdgcn_s_barrier();
  __builtin_amdgcn_sched_barrier(0);
  s16x8 af[4], bfr[4];
#pragma unroll
  for (int mi = 0; mi < 4; ++mi)
    af[mi] = *(const s16x8*)(AsR + ((H * 4 + (lane >> 4)) * 4 + mi) * 256 + (lane & 15) * 16);
#pragma unroll
  for (int ni = 0; ni < 4; ++ni)
    bfr[ni] = *(const s16x8*)(BbR + ((lane >> 4) * 32 + wid * 4 + ni) * 256 + (lane & 15) * 16);
  if (WRA) {
    US8 o{f2bf(aW0.x), f2bf(aW0.y), f2bf(aW0.z), f2bf(aW0.w),
          f2bf(aW1.x), f2bf(aW1.y), f2bf(aW1.z), f2bf(aW1.w)};
    *(US8*)(AsW + sDst) = o;
  }
  asm volatile("s_waitcnt lgkmcnt(0)" ::: "memory");
  __builtin_amdgcn_s_barrier();
  __builtin_amdgcn_sched_barrier(0);
#pragma unroll
  for (int mi = 0; mi < 4; ++mi)
#pragma unroll
    for (int ni = 0; ni < 4; ++ni)
      acc[mi][ni] = __builtin_amdgcn_mfma_f32_16x16x32_bf16(af[mi], bfr[ni], acc[mi][ni], 0, 0, 0);
}

__global__ __launch_bounds__(512, 4) void k_gemm1f(
    const float* __restrict__ enc, const unsigned short* __restrict__ Web,
    const float* __restrict__ be, const unsigned short* __restrict__ Waeb,
    const float* __restrict__ bbw, const float* __restrict__ vv,
    unsigned short* __restrict__ eo, float* __restrict__ sp) {
  __shared__ char smem[81920];  // 80 KB
  const int t = threadIdx.x, lane = t & 63, wid = t >> 6;
  const int m0 = blockIdx.x * 64;
  const float* enc_m0 = enc + (size_t)m0 * FF;
  f32x4 acc[4][4] = {};

  // staging coords
  const int sRow = t & 63;
  const int sKb  = t >> 6;  // 0..7
  const int sDst = (sKb * 4 + (sRow >> 4)) * 256 + (sRow & 15) * 16;
  int bRow[4], bKb[4];
#pragma unroll
  for (int i = 0; i < 4; ++i) {
    int idx = i * 512 + t;
    bRow[i] = ((idx >> 4) & 31) * 16 + (idx & 15);
    bKb[i]  = idx >> 9;  // 0..3
  }

  // ---- prologue: B(0)->Bb0; A(0)->slot0 (-> As0); A(1)->slot1; full drain ----
  f32x4 s00, s01, s10, s11;
#pragma unroll
  for (int i = 0; i < 4; ++i) {
    int idx = i * 512 + t;
    gload_lds16(Web + (size_t)bRow[i] * FF + bKb[i] * 8, smem + 16384 + idx * 16);
  }
  {
    const float* p = enc_m0 + (size_t)sRow * FF + sKb * 8;
    s00 = *(const f32x4*)p;
    s01 = *(const f32x4*)(p + 4);
    const float* q = enc_m0 + (size_t)sRow * FF + 64 + sKb * 8;
    s10 = *(const f32x4*)q;
    s11 = *(const f32x4*)(q + 4);
    US8 o{f2bf(s00.x), f2bf(s00.y), f2bf(s00.z), f2bf(s00.w),
          f2bf(s01.x), f2bf(s01.y), f2bf(s01.z), f2bf(s01.w)};
    *(US8*)(smem + sDst) = o;
  }
  asm volatile("s_waitcnt vmcnt(0) lgkmcnt(0)" ::: "memory");
  __builtin_amdgcn_s_barrier();
  __builtin_amdgcn_sched_barrier(0);

  // ---- main loop: steps 0..29 (uniform), tail 30,31 ----
  int kt = 0;
#pragma unroll 1
  for (int ss = 0; ss < 15; ++ss) {
    // s even (SPAR=0): load A(s+2)->slot0, write A(s+1) from slot1
    phase<0, 0, true, true, false, 6>(enc_m0, Web, smem, kt, t, lane, wid, sRow, sKb, sDst, bRow, bKb, s00, s01, s10, s11, acc);
    phase<0, 1, true, false, true, 6>(enc_m0, Web, smem, kt, t, lane, wid, sRow, sKb, sDst, bRow, bKb, s00, s01, s10, s11, acc);
    // s odd (SPAR=1): load A(s+2)->slot1, write A(s+1) from slot0
    phase<1, 0, true, true, false, 6>(enc_m0, Web, smem, kt + 64, t, lane, wid, sRow, sKb, sDst, bRow, bKb, s10, s11, s00, s01, acc);
    phase<1, 1, true, false, true, 6>(enc_m0, Web, smem, kt + 64, t, lane, wid, sRow, sKb, sDst, bRow, bKb, s10, s11, s00, s01, acc);
    kt += 128;
  }
  // s=30 (SPAR=0): no A load; write A(31) from slot1
  phase<0, 0, true, false, false, 4>(enc_m0, Web, smem, 1920, t, lane, wid, sRow, sKb, sDst, bRow, bKb, s00, s01, s10, s11, acc);
  phase<0, 1, true, false, true, 4>(enc_m0, Web, smem, 1920, t, lane, wid, sRow, sKb, sDst, bRow, bKb, s00, s01, s10, s11, acc);
  // s=31 (SPAR=1): H0 stages B(63); H1 computes only
  phase<1, 0, true, false, false, 4>(enc_m0, Web, smem, 1984, t, lane, wid, sRow, sKb, sDst, bRow, bKb, s10, s11, s00, s01, acc);
  phase<1, 1, false, false, false, 0>(enc_m0, Web, smem, 1984, t, lane, wid, sRow, sKb, sDst, bRow, bKb, s10, s11, s00, s01, acc);

  // ---- epilogue 1: acc (+be) -> swizzled Cs @16KB (aliases B buffers) ----
  unsigned short* Cs = (unsigned short*)(smem + 16384);  // [64][512] bf16, byte = r*1024 + ((c*2)^((r&7)<<4))
#pragma unroll
  for (int ni = 0; ni < 4; ++ni) {
    int col = wid * 64 + ni * 16 + (lane & 15);
    float bev = be[col];
#pragma unroll
    for (int mi = 0; mi < 4; ++mi)
#pragma unroll
      for (int j = 0; j < 4; ++j) {
        int row = mi * 16 + (lane >> 4) * 4 + j;
        int byte = row * 1024 + ((col * 2) ^ ((row & 7) << 4));
        *(unsigned short*)((char*)Cs + byte) = f2bf(acc[mi][ni][j] + bev);
      }
  }
  __syncthreads();

  // ---- epilogue 2: coalesced eo store ----
#pragma unroll
  for (int i = 0; i < 8; ++i) {
    int idx = i * 512 + t, row = idx >> 6, c = idx & 63;
    int byte = row * 1024 + ((c * 16) ^ ((row & 7) << 4));
    *(US8*)(eo + (size_t)(m0 + row) * HH + c * 8) = *(const US8*)((const char*)Cs + byte);
  }

  // ---- epilogue 3: GEMM2  E = eoTile @ Waeb^T (B from L2) ----
  f32x4 acc2[4][4] = {};
#pragma unroll 1
  for (int kt2 = 0; kt2 < HH; kt2 += 64) {
#pragma unroll
    for (int ks = 0; ks < 2; ++ks) {
      int k2 = kt2 + ks * 32 + (lane >> 4) * 8;
      s16x8 af[4], bfr[4];
#pragma unroll
      for (int mi = 0; mi < 4; ++mi) {
        int row = mi * 16 + (lane & 15);
        int byte = row * 1024 + ((k2 * 2) ^ ((row & 7) << 4));
        af[mi] = *(const s16x8*)((const char*)Cs + byte);
      }
#pragma unroll
      for (int ni = 0; ni < 4; ++ni) {
        int nrow = wid * 64 + ni * 16 + (lane & 15);
        bfr[ni] = *(const s16x8*)(Waeb + (size_t)nrow * HH + k2);
      }
#pragma unroll
      for (int mi = 0; mi < 4; ++mi)
#pragma unroll
        for (int ni = 0; ni < 4; ++ni)
          acc2[mi][ni] = __builtin_amdgcn_mfma_f32_16x16x32_bf16(af[mi], bfr[ni], acc2[mi][ni], 0, 0, 0);
    }
  }

  // ---- epilogue 4: scores = sum_n tanh(E + bb) * v ----
  const int b = m0 >> 11;
  float vcol[4], bcol[4];
#pragma unroll
  for (int ni = 0; ni < 4; ++ni) {
    int col = wid * 64 + ni * 16 + (lane & 15);
    vcol[ni] = vv[col];
    bcol[ni] = bbw[b * HH + col];
  }
  float ps[4][4];
#pragma unroll
  for (int mi = 0; mi < 4; ++mi)
#pragma unroll
    for (int j = 0; j < 4; ++j) {
      float s = 0.f;
#pragma unroll
      for (int ni = 0; ni < 4; ++ni)
        s += tanhf(acc2[mi][ni][j] + bcol[ni]) * vcol[ni];
      ps[mi][j] = s;
    }
#pragma unroll
  for (int m = 1; m < 16; m <<= 1)
#pragma unroll
    for (int mi = 0; mi < 4; ++mi)
#pragma unroll
      for (int j = 0; j < 4; ++j) ps[mi][j] += __shfl_xor(ps[mi][j], m);
  float* red = (float*)smem;  // 2KB @0 (As region dead; Cs untouched)
  if ((lane & 15) == 0) {
#pragma unroll
    for (int mi = 0; mi < 4; ++mi)
#pragma unroll
      for (int j = 0; j < 4; ++j)
        red[wid * 64 + mi * 16 + (lane >> 4) * 4 + j] = ps[mi][j];
  }
  __syncthreads();
  if (t < 64) {
    float s = 0.f;
#pragma unroll
    for (int w = 0; w < 8; ++w) s += red[w * 64 + t];
    sp[m0 + t] = s;
  }
}

// ---- softmax over S per batch ----
__global__ void k_softmax(const float* __restrict__ sp, float* __restrict__ attn) {
  const int b = blockIdx.x, t = threadIdx.x, lane = t & 63, wid = t >> 6;
  __shared__ float red[4];
  float vals[8], lmax = -3.0e38f;
#pragma unroll
  for (int i = 0; i < 8; ++i) {
    float x = sp[b * SS + t + i * 256];
    vals[i] = x;
    lmax = fmaxf(lmax, x);
  }
#pragma unroll
  for (int m = 32; m; m >>= 1) lmax = fmaxf(lmax, __shfl_xor(lmax, m));
  if (lane == 0) red[wid] = lmax;
  __syncthreads();
  lmax = fmaxf(fmaxf(red[0], red[1]), fmaxf(red[2], red[3]));
  __syncthreads();
  float lsum = 0.f;
#pragma unroll
  for (int i = 0; i < 8; ++i) {
    vals[i] = __expf(vals[i] - lmax);
    lsum += vals[i];
  }
#pragma unroll
  for (int m = 32; m; m >>= 1) lsum += __shfl_xor(lsum, m);
  if (lane == 0) red[wid] = lsum;
  __syncthreads();
  float inv = 1.0f / (red[0] + red[1] + red[2] + red[3]);
#pragma unroll
  for (int i = 0; i < 8; ++i) attn[b * SS + t + i * 256] = vals[i] * inv;
}

// ---- context stage 1 ----
__global__ __launch_bounds__(512) void k_ctx1(const unsigned short* __restrict__ eo,
                                              const float* __restrict__ attn,
                                              float* __restrict__ cp) {
  __shared__ float red[8][512];
  const int b = blockIdx.x >> 4, ch = blockIdx.x & 15, t = threadIdx.x;
  const int tg = t & 63, sg = t >> 6;
  const float* aw = attn + b * SS + ch * 128;
  float acc[8] = {};
#pragma unroll 4
  for (int i = 0; i < 16; ++i) {
    int s = sg + i * 8;
    float w = aw[s];
    US8 vv8 = *(const US8*)(eo + (size_t)(b * SS + ch * 128 + s) * HH + tg * 8);
#pragma unroll
    for (int j = 0; j < 8; ++j) acc[j] += w * bf2f(vv8.s[j]);
  }
#pragma unroll
  for (int j = 0; j < 8; ++j) red[sg][tg * 8 + j] = acc[j];
  __syncthreads();
  float a = 0.f;
#pragma unroll
  for (int g = 0; g < 8; ++g) a += red[g][t];
  cp[(size_t)blockIdx.x * HH + t] = a;
}

// ---- context stage 2 ----
__global__ void k_ctx2(const float* __restrict__ cp, float* __restrict__ ctx) {
  const int b = blockIdx.x, h = threadIdx.x;
  float a = 0.f;
#pragma unroll
  for (int c = 0; c < 16; ++c) a += cp[(size_t)(b * 16 + c) * HH + h];
  ctx[b * HH + h] = a;
}

extern "C" void kernel_launch(void* const* d_in, const int* in_sizes, int n_in,
                              void* d_out, int out_size, void* d_ws, size_t ws_size,
                              hipStream_t stream) {
  (void)in_sizes; (void)n_in; (void)out_size; (void)ws_size;
  const float* hidden = (const float*)d_in[0];
  const float* enc    = (const float*)d_in[1];
  const float* We     = (const float*)d_in[2];
  const float* be     = (const float*)d_in[3];
  const float* Wh     = (const float*)d_in[4];
  const float* bh     = (const float*)d_in[5];
  const float* Wa     = (const float*)d_in[6];
  const float* ba     = (const float*)d_in[7];
  const float* v      = (const float*)d_in[8];

  float* out  = (float*)d_out;
  float* ctx  = out;            // 16*512
  float* attn = out + BB * HH;  // 16*2048

  char* ws = (char*)d_ws;
  unsigned short* Web  = (unsigned short*)ws;  ws += (size_t)HH * FF * 2;     // 2 MB
  unsigned short* Waeb = (unsigned short*)ws;  ws += (size_t)HH * HH * 2;     // 512 KB
  float* h_ws  = (float*)ws;                   ws += (size_t)BB * HH * 4;     // 32 KB
  float* bb_ws = (float*)ws;                   ws += (size_t)BB * HH * 4;     // 32 KB
  unsigned short* eo = (unsigned short*)ws;    ws += (size_t)MM * HH * 2;     // 32 MB
  float* sp = (float*)ws;                      ws += (size_t)MM * 4;          // 128 KB
  float* cp = (float*)ws;                      ws += (size_t)BB * 16 * HH * 4;// 512 KB

  k_conv<<<1280, 256, 0, stream>>>(We, Wa, Web, Waeb);
  k_h<<<2048, 256, 0, stream>>>(hidden, Wh, bh, h_ws);
  k_bb<<<2048, 256, 0, stream>>>(h_ws, Wa, ba, bb_ws);
  k_gemm1f<<<512, 512, 0, stream>>>(enc, Web, be, Waeb, bb_ws, v, eo, sp);
  k_softmax<<<16, 256, 0, stream>>>(sp, attn);
  k_ctx1<<<256, 512, 0, stream>>>(eo, attn, cp);
  k_ctx2<<<16, 512, 0, stream>>>(cp, ctx);
}

// Round 10
// 170.529 us; speedup vs baseline: 1.8109x; 1.8109x over previous
//
#include <hip/hip_runtime.h>
#include <math.h>

#define HH 512
#define FF 2048
#define BB 16
#define SS 2048
#define MM 32768  // BB*SS

using f32x4 = __attribute__((ext_vector_type(4))) float;
using s16x8 = __attribute__((ext_vector_type(8))) short;

struct __align__(8)  US4 { unsigned short x, y, z, w; };
struct __align__(16) US8 { unsigned short s[8]; };

__device__ __forceinline__ unsigned short f2bf(float f) {
  unsigned int u = __builtin_bit_cast(unsigned int, f);
  u += 0x7fffu + ((u >> 16) & 1u);
  return (unsigned short)(u >> 16);
}
__device__ __forceinline__ float bf2f(unsigned short u) {
  unsigned int x = ((unsigned int)u) << 16;
  return __builtin_bit_cast(float, x);
}
__device__ __forceinline__ void gload_lds16(const void* g, void* l) {
  __builtin_amdgcn_global_load_lds(
      (const __attribute__((address_space(1))) unsigned int*)g,
      (__attribute__((address_space(3))) unsigned int*)l, 16, 0, 0);
}

// ---- weight conversions (merged) ----
__global__ void k_conv(const float* __restrict__ We, const float* __restrict__ Wa,
                       unsigned short* __restrict__ OWe, unsigned short* __restrict__ OWa) {
  int bid = blockIdx.x, t = threadIdx.x;
  if (bid < 1024) {
    int idx = bid * 256 + t;  // < 262144
    f32x4 x = *(const f32x4*)(We + (size_t)idx * 4);
    US4 p{f2bf(x.x), f2bf(x.y), f2bf(x.z), f2bf(x.w)};
    *(US4*)(OWe + (size_t)idx * 4) = p;
  } else {
    int idx = (bid - 1024) * 256 + t;  // < 65536
    int k = idx >> 7, h4 = idx & 127;
    f32x4 x = *(const f32x4*)(Wa + (size_t)k * 1024 + 512 + h4 * 4);
    US4 p{f2bf(x.x), f2bf(x.y), f2bf(x.z), f2bf(x.w)};
    *(US4*)(OWa + (size_t)idx * 4) = p;
  }
}

// ---- h = hidden[-1] @ Wh.T + bh ----
__global__ void k_h(const float* __restrict__ hidden, const float* __restrict__ Wh,
                    const float* __restrict__ bh, float* __restrict__ h_ws) {
  int t = threadIdx.x, lane = t & 63, wid = t >> 6;
  int out = blockIdx.x * 4 + wid;  // < 8192
  int b = out >> 9, j = out & 511;
  const float* hr = hidden + (1) * BB * FF + b * FF;
  const float* wr = Wh + (size_t)j * FF;
  float a = 0.f;
#pragma unroll
  for (int i = 0; i < 8; ++i) {
    int o = i * 256 + lane * 4;
    f32x4 x = *(const f32x4*)(hr + o);
    f32x4 y = *(const f32x4*)(wr + o);
    a += x.x * y.x + x.y * y.y + x.z * y.z + x.w * y.w;
  }
#pragma unroll
  for (int m = 32; m; m >>= 1) a += __shfl_xor(a, m);
  if (lane == 0) h_ws[out] = a + bh[j];
}

// ---- bb[b][k] = ba[k] + h[b] . Wa[k, 0:512] ----
__global__ void k_bb(const float* __restrict__ h_ws, const float* __restrict__ Wa,
                     const float* __restrict__ ba, float* __restrict__ bb_ws) {
  int t = threadIdx.x, lane = t & 63, wid = t >> 6;
  int out = blockIdx.x * 4 + wid;  // < 8192
  int b = out >> 9, k = out & 511;
  const float* hr = h_ws + b * HH;
  const float* wa = Wa + (size_t)k * 1024;
  float a = 0.f;
#pragma unroll
  for (int i = 0; i < 2; ++i) {
    int o = i * 256 + lane * 4;
    f32x4 x = *(const f32x4*)(hr + o);
    f32x4 y = *(const f32x4*)(wa + o);
    a += x.x * y.x + x.y * y.y + x.z * y.z + x.w * y.w;
  }
#pragma unroll
  for (int m = 32; m; m >>= 1) a += __shfl_xor(a, m);
  if (lane == 0) bb_ws[out] = a + ba[k];
}

// ====== fused GEMM1 + GEMM2 + scores (R5 structure + counted waits) ======
// EXACT R5 geometry (best so far): M=64 x N=512, 512 thr / 8 waves, BK=64,
// single-buffered LDS 72KB (As 8KB + Bs 64KB) => 2 blocks/CU.
// Delta vs R5 (the 168.8us version):
//  * barrier1 = s_waitcnt vmcnt(2) lgkmcnt(0); s_barrier  -- B landed, the 2
//    A-prefetch loads stay IN FLIGHT across the whole compute phase (T4).
//  * barrier2 = s_waitcnt lgkmcnt(0); s_barrier           -- NO vm drain.
//  * epilogue GEMM2 fully unrolled so the compiler pipelines Waeb L2 loads.
__global__ __launch_bounds__(512, 4) void k_gemm1f(
    const float* __restrict__ enc, const unsigned short* __restrict__ Web,
    const float* __restrict__ be, const unsigned short* __restrict__ Waeb,
    const float* __restrict__ bbw, const float* __restrict__ vv,
    unsigned short* __restrict__ eo, float* __restrict__ sp) {
  __shared__ unsigned short smem[36864];  // 72 KB
  unsigned short* As = smem;              // [64][64] swizzled
  unsigned short* Bs = smem + 4096;       // [512][64] swizzled
  const int t = threadIdx.x, lane = t & 63, wid = t >> 6;
  const int m0 = blockIdx.x * 64;
  const float* enc_m0 = enc + (size_t)m0 * FF;
  f32x4 acc[4][4] = {};

  f32x4 areg[2];
#pragma unroll
  for (int i = 0; i < 2; ++i) {
    int idx = i * 512 + t, row = idx >> 4, c4 = idx & 15;
    areg[i] = *(const f32x4*)(enc_m0 + (size_t)row * FF + c4 * 4);
  }

#pragma unroll 1
  for (int kt = 0; kt < FF; kt += 64) {
    // B tile: rows 0..511 of Web, pre-swizzled source chunk -> linear LDS
#pragma unroll
    for (int i = 0; i < 8; ++i) {
      int idx = i * 512 + t, row = idx >> 3, c = idx & 7, sc = c ^ (row & 7);
      gload_lds16(Web + (size_t)row * FF + kt + sc * 8, Bs + idx * 8);
    }
    // A tile: cvt prefetched regs (compiler auto-waits their vmcnt) -> LDS
#pragma unroll
    for (int i = 0; i < 2; ++i) {
      int idx = i * 512 + t, row = idx >> 4, c4 = idx & 15;
      f32x4 x = areg[i];
      US4 p{f2bf(x.x), f2bf(x.y), f2bf(x.z), f2bf(x.w)};
      int byte = row * 128 + ((c4 * 8) ^ ((row & 7) << 4));
      *(US4*)((char*)As + byte) = p;
    }
    // prefetch next A (stays in flight across the compute phase)
    {
      int ktn = (kt + 64 < FF) ? kt + 64 : 0;
#pragma unroll
      for (int i = 0; i < 2; ++i) {
        int idx = i * 512 + t, row = idx >> 4, c4 = idx & 15;
        areg[i] = *(const f32x4*)(enc_m0 + (size_t)row * FF + ktn + c4 * 4);
      }
    }
    // barrier1: B (4 gload_lds) must land; 2 A loads keep flying
    asm volatile("s_waitcnt vmcnt(2) lgkmcnt(0)" ::: "memory");
    __builtin_amdgcn_s_barrier();
    __builtin_amdgcn_sched_barrier(0);
#pragma unroll
    for (int ks = 0; ks < 2; ++ks) {
      s16x8 af[4], bfr[4];
#pragma unroll
      for (int mi = 0; mi < 4; ++mi) {
        int row = mi * 16 + (lane & 15);
        int byte = row * 128 + (((ks * 64) + (lane >> 4) * 16) ^ ((row & 7) << 4));
        af[mi] = *(const s16x8*)((const char*)As + byte);
      }
#pragma unroll
      for (int ni = 0; ni < 4; ++ni) {
        int row = wid * 64 + ni * 16 + (lane & 15);
        int byte = row * 128 + (((ks * 64) + (lane >> 4) * 16) ^ ((row & 7) << 4));
        bfr[ni] = *(const s16x8*)((const char*)Bs + byte);
      }
#pragma unroll
      for (int mi = 0; mi < 4; ++mi)
#pragma unroll
        for (int ni = 0; ni < 4; ++ni)
          acc[mi][ni] = __builtin_amdgcn_mfma_f32_16x16x32_bf16(af[mi], bfr[ni], acc[mi][ni], 0, 0, 0);
    }
    // barrier2: LDS reads retired (lgkm only); A loads still in flight
    asm volatile("s_waitcnt lgkmcnt(0)" ::: "memory");
    __builtin_amdgcn_s_barrier();
    __builtin_amdgcn_sched_barrier(0);
  }

  // ---- epilogue 1: acc (+be) -> swizzled Cs (Bs region, 64KB) ----
  unsigned short* Cs = smem + 4096;  // [64][512] bf16, byte = r*1024 + ((c*2)^((r&7)<<4))
#pragma unroll
  for (int ni = 0; ni < 4; ++ni) {
    int col = wid * 64 + ni * 16 + (lane & 15);
    float bev = be[col];
#pragma unroll
    for (int mi = 0; mi < 4; ++mi)
#pragma unroll
      for (int j = 0; j < 4; ++j) {
        int row = mi * 16 + (lane >> 4) * 4 + j;
        int byte = row * 1024 + ((col * 2) ^ ((row & 7) << 4));
        *(unsigned short*)((char*)Cs + byte) = f2bf(acc[mi][ni][j] + bev);
      }
  }
  __syncthreads();

  // ---- epilogue 2: coalesced eo store (de-swizzled US8 reads) ----
#pragma unroll
  for (int i = 0; i < 8; ++i) {
    int idx = i * 512 + t, row = idx >> 6, c = idx & 63;
    int byte = row * 1024 + ((c * 16) ^ ((row & 7) << 4));
    *(US8*)(eo + (size_t)(m0 + row) * HH + c * 8) = *(const US8*)((const char*)Cs + byte);
  }

  // ---- epilogue 3: GEMM2  E(64x64 per wave) = eoTile @ Waeb^T ----
  // FULLY unrolled: compiler hoists the Waeb L2 loads across slices.
  f32x4 acc2[4][4] = {};
#pragma unroll
  for (int kt2 = 0; kt2 < HH; kt2 += 64) {
#pragma unroll
    for (int ks = 0; ks < 2; ++ks) {
      int k2 = kt2 + ks * 32 + (lane >> 4) * 8;
      s16x8 af[4], bfr[4];
#pragma unroll
      for (int mi = 0; mi < 4; ++mi) {
        int row = mi * 16 + (lane & 15);
        int byte = row * 1024 + ((k2 * 2) ^ ((row & 7) << 4));
        af[mi] = *(const s16x8*)((const char*)Cs + byte);
      }
#pragma unroll
      for (int ni = 0; ni < 4; ++ni) {
        int nrow = wid * 64 + ni * 16 + (lane & 15);
        bfr[ni] = *(const s16x8*)(Waeb + (size_t)nrow * HH + k2);
      }
#pragma unroll
      for (int mi = 0; mi < 4; ++mi)
#pragma unroll
        for (int ni = 0; ni < 4; ++ni)
          acc2[mi][ni] = __builtin_amdgcn_mfma_f32_16x16x32_bf16(af[mi], bfr[ni], acc2[mi][ni], 0, 0, 0);
    }
  }

  // ---- epilogue 4: scores = sum_n tanh(E + bb) * v ----
  const int b = m0 >> 11;
  float vcol[4], bcol[4];
#pragma unroll
  for (int ni = 0; ni < 4; ++ni) {
    int col = wid * 64 + ni * 16 + (lane & 15);
    vcol[ni] = vv[col];
    bcol[ni] = bbw[b * HH + col];
  }
  float ps[4][4];
#pragma unroll
  for (int mi = 0; mi < 4; ++mi)
#pragma unroll
    for (int j = 0; j < 4; ++j) {
      float s = 0.f;
#pragma unroll
      for (int ni = 0; ni < 4; ++ni)
        s += tanhf(acc2[mi][ni][j] + bcol[ni]) * vcol[ni];
      ps[mi][j] = s;
    }
#pragma unroll
  for (int m = 1; m < 16; m <<= 1)
#pragma unroll
    for (int mi = 0; mi < 4; ++mi)
#pragma unroll
      for (int j = 0; j < 4; ++j) ps[mi][j] += __shfl_xor(ps[mi][j], m);
  float* red = (float*)smem;  // 2KB @0 (As region; Cs untouched)
  if ((lane & 15) == 0) {
#pragma unroll
    for (int mi = 0; mi < 4; ++mi)
#pragma unroll
      for (int j = 0; j < 4; ++j)
        red[wid * 64 + mi * 16 + (lane >> 4) * 4 + j] = ps[mi][j];
  }
  __syncthreads();
  if (t < 64) {
    float s = 0.f;
#pragma unroll
    for (int w = 0; w < 8; ++w) s += red[w * 64 + t];
    sp[m0 + t] = s;
  }
}

// ---- softmax over S per batch ----
__global__ void k_softmax(const float* __restrict__ sp, float* __restrict__ attn) {
  const int b = blockIdx.x, t = threadIdx.x, lane = t & 63, wid = t >> 6;
  __shared__ float red[4];
  float vals[8], lmax = -3.0e38f;
#pragma unroll
  for (int i = 0; i < 8; ++i) {
    float x = sp[b * SS + t + i * 256];
    vals[i] = x;
    lmax = fmaxf(lmax, x);
  }
#pragma unroll
  for (int m = 32; m; m >>= 1) lmax = fmaxf(lmax, __shfl_xor(lmax, m));
  if (lane == 0) red[wid] = lmax;
  __syncthreads();
  lmax = fmaxf(fmaxf(red[0], red[1]), fmaxf(red[2], red[3]));
  __syncthreads();
  float lsum = 0.f;
#pragma unroll
  for (int i = 0; i < 8; ++i) {
    vals[i] = __expf(vals[i] - lmax);
    lsum += vals[i];
  }
#pragma unroll
  for (int m = 32; m; m >>= 1) lsum += __shfl_xor(lsum, m);
  if (lane == 0) red[wid] = lsum;
  __syncthreads();
  float inv = 1.0f / (red[0] + red[1] + red[2] + red[3]);
#pragma unroll
  for (int i = 0; i < 8; ++i) attn[b * SS + t + i * 256] = vals[i] * inv;
}

// ---- context stage 1 ----
__global__ __launch_bounds__(512) void k_ctx1(const unsigned short* __restrict__ eo,
                                              const float* __restrict__ attn,
                                              float* __restrict__ cp) {
  __shared__ float red[8][512];
  const int b = blockIdx.x >> 4, ch = blockIdx.x & 15, t = threadIdx.x;
  const int tg = t & 63, sg = t >> 6;
  const float* aw = attn + b * SS + ch * 128;
  float acc[8] = {};
#pragma unroll 4
  for (int i = 0; i < 16; ++i) {
    int s = sg + i * 8;
    float w = aw[s];
    US8 vv8 = *(const US8*)(eo + (size_t)(b * SS + ch * 128 + s) * HH + tg * 8);
#pragma unroll
    for (int j = 0; j < 8; ++j) acc[j] += w * bf2f(vv8.s[j]);
  }
#pragma unroll
  for (int j = 0; j < 8; ++j) red[sg][tg * 8 + j] = acc[j];
  __syncthreads();
  float a = 0.f;
#pragma unroll
  for (int g = 0; g < 8; ++g) a += red[g][t];
  cp[(size_t)blockIdx.x * HH + t] = a;
}

// ---- context stage 2 ----
__global__ void k_ctx2(const float* __restrict__ cp, float* __restrict__ ctx) {
  const int b = blockIdx.x, h = threadIdx.x;
  float a = 0.f;
#pragma unroll
  for (int c = 0; c < 16; ++c) a += cp[(size_t)(b * 16 + c) * HH + h];
  ctx[b * HH + h] = a;
}

extern "C" void kernel_launch(void* const* d_in, const int* in_sizes, int n_in,
                              void* d_out, int out_size, void* d_ws, size_t ws_size,
                              hipStream_t stream) {
  (void)in_sizes; (void)n_in; (void)out_size; (void)ws_size;
  const float* hidden = (const float*)d_in[0];
  const float* enc    = (const float*)d_in[1];
  const float* We     = (const float*)d_in[2];
  const float* be     = (const float*)d_in[3];
  const float* Wh     = (const float*)d_in[4];
  const float* bh     = (const float*)d_in[5];
  const float* Wa     = (const float*)d_in[6];
  const float* ba     = (const float*)d_in[7];
  const float* v      = (const float*)d_in[8];

  float* out  = (float*)d_out;
  float* ctx  = out;            // 16*512
  float* attn = out + BB * HH;  // 16*2048

  char* ws = (char*)d_ws;
  unsigned short* Web  = (unsigned short*)ws;  ws += (size_t)HH * FF * 2;     // 2 MB
  unsigned short* Waeb = (unsigned short*)ws;  ws += (size_t)HH * HH * 2;     // 512 KB
  float* h_ws  = (float*)ws;                   ws += (size_t)BB * HH * 4;     // 32 KB
  float* bb_ws = (float*)ws;                   ws += (size_t)BB * HH * 4;     // 32 KB
  unsigned short* eo = (unsigned short*)ws;    ws += (size_t)MM * HH * 2;     // 32 MB
  float* sp = (float*)ws;                      ws += (size_t)MM * 4;          // 128 KB
  float* cp = (float*)ws;                      ws += (size_t)BB * 16 * HH * 4;// 512 KB

  k_conv<<<1280, 256, 0, stream>>>(We, Wa, Web, Waeb);
  k_h<<<2048, 256, 0, stream>>>(hidden, Wh, bh, h_ws);
  k_bb<<<2048, 256, 0, stream>>>(h_ws, Wa, ba, bb_ws);
  k_gemm1f<<<512, 512, 0, stream>>>(enc, Web, be, Waeb, bb_ws, v, eo, sp);
  k_softmax<<<16, 256, 0, stream>>>(sp, attn);
  k_ctx1<<<256, 512, 0, stream>>>(eo, attn, cp);
  k_ctx2<<<16, 512, 0, stream>>>(cp, ctx);
}